// Round 1
// baseline (71.551 us; speedup 1.0000x reference)
//
#include <hip/hip_runtime.h>

#define B_ 256
#define K_ 512
#define D_ 64
#define KD_ 576   // K + D
#define LOG2E 1.44269504088896340736f

__device__ __forceinline__ float fexp2(float x) {
#if __has_builtin(__builtin_amdgcn_exp2f)
    return __builtin_amdgcn_exp2f(x);
#else
    float r; asm("v_exp_f32 %0, %1" : "=v"(r) : "v"(x)); return r;
#endif
}
__device__ __forceinline__ float frcp(float x) {
#if __has_builtin(__builtin_amdgcn_rcpf)
    return __builtin_amdgcn_rcpf(x);
#else
    float r; asm("v_rcp_f32 %0, %1" : "=v"(r) : "v"(x)); return r;
#endif
}
__device__ __forceinline__ float fsig(float x) {
    // sigmoid(x) = 1 / (1 + 2^(-x*log2e))
    return frcp(1.0f + fexp2(-LOG2E * x));
}

// ---------------------------------------------------------------------------
// K1: S1[b,n] = sigmoid(stu_table[stu_id[b]] . kn_table[n]),  S2 likewise (exer)
// grid: B_ blocks x 256 threads
// ---------------------------------------------------------------------------
__global__ void __launch_bounds__(256) kS(const int* __restrict__ sid,
                                          const int* __restrict__ eid,
                                          const float* __restrict__ stu_t,
                                          const float* __restrict__ exer_t,
                                          const float* __restrict__ kn_t,
                                          float* __restrict__ S1,
                                          float* __restrict__ S2) {
    __shared__ float sr[D_];
    __shared__ float er[D_];
    const int b = blockIdx.x;
    if (threadIdx.x < D_)
        sr[threadIdx.x] = stu_t[(size_t)sid[b] * D_ + threadIdx.x];
    else if (threadIdx.x < 2 * D_)
        er[threadIdx.x - D_] = exer_t[(size_t)eid[b] * D_ + (threadIdx.x - D_)];
    __syncthreads();
    for (int n = threadIdx.x; n < K_; n += 256) {
        const float* kr = kn_t + (size_t)n * D_;
        float a = 0.f, c = 0.f;
#pragma unroll
        for (int d = 0; d < D_; d += 4) {
            float4 kv = *(const float4*)(kr + d);
            a = fmaf(sr[d], kv.x, a); a = fmaf(sr[d+1], kv.y, a);
            a = fmaf(sr[d+2], kv.z, a); a = fmaf(sr[d+3], kv.w, a);
            c = fmaf(er[d], kv.x, c); c = fmaf(er[d+1], kv.y, c);
            c = fmaf(er[d+2], kv.z, c); c = fmaf(er[d+3], kv.w, c);
        }
        S1[b * K_ + n] = fsig(a);
        S2[b * K_ + n] = fsig(c);
    }
}

// ---------------------------------------------------------------------------
// K2: E[b,m] = exp(-(S[b,:] . W[m, 0:K]))   for W1/S1 (z=0) and W2/S2 (z=1)
// grid: (K_/64, B_/4, 2), block 64 (one wave). S loads are wave-uniform.
// ---------------------------------------------------------------------------
__global__ void __launch_bounds__(64) kA(const float* __restrict__ Sbase,
                                         const float* __restrict__ W1,
                                         const float* __restrict__ W2,
                                         float* __restrict__ Ebase) {
    const int mat = blockIdx.z;
    const float* W = mat ? W2 : W1;
    const float* S = Sbase + (size_t)mat * (B_ * K_);
    float* Eo = Ebase + (size_t)mat * (B_ * K_);
    const int m = blockIdx.x * 64 + threadIdx.x;
    const int b0 = blockIdx.y * 4;
    const float* wrow = W + (size_t)m * KD_;
    const float* s0 = S + (size_t)(b0 + 0) * K_;
    const float* s1 = S + (size_t)(b0 + 1) * K_;
    const float* s2 = S + (size_t)(b0 + 2) * K_;
    const float* s3 = S + (size_t)(b0 + 3) * K_;
    float a0 = 0.f, a1 = 0.f, a2 = 0.f, a3 = 0.f;
    for (int n = 0; n < K_; n += 4) {
        float4 w = *(const float4*)(wrow + n);
        float4 v0 = *(const float4*)(s0 + n);
        float4 v1 = *(const float4*)(s1 + n);
        float4 v2 = *(const float4*)(s2 + n);
        float4 v3 = *(const float4*)(s3 + n);
        a0 = fmaf(v0.x, w.x, a0); a0 = fmaf(v0.y, w.y, a0);
        a0 = fmaf(v0.z, w.z, a0); a0 = fmaf(v0.w, w.w, a0);
        a1 = fmaf(v1.x, w.x, a1); a1 = fmaf(v1.y, w.y, a1);
        a1 = fmaf(v1.z, w.z, a1); a1 = fmaf(v1.w, w.w, a1);
        a2 = fmaf(v2.x, w.x, a2); a2 = fmaf(v2.y, w.y, a2);
        a2 = fmaf(v2.z, w.z, a2); a2 = fmaf(v2.w, w.w, a2);
        a3 = fmaf(v3.x, w.x, a3); a3 = fmaf(v3.y, w.y, a3);
        a3 = fmaf(v3.z, w.z, a3); a3 = fmaf(v3.w, w.w, a3);
    }
    Eo[(size_t)(b0 + 0) * K_ + m] = fexp2(-LOG2E * a0);
    Eo[(size_t)(b0 + 1) * K_ + m] = fexp2(-LOG2E * a1);
    Eo[(size_t)(b0 + 2) * K_ + m] = fexp2(-LOG2E * a2);
    Eo[(size_t)(b0 + 3) * K_ + m] = fexp2(-LOG2E * a3);
}

// ---------------------------------------------------------------------------
// KC: F[k,n] = exp(-(kn_table[k,:] . W[n, K:K+D]))  for W1 (y=0), W2 (y=1)
// grid: (K_/8, 2), block 256
// ---------------------------------------------------------------------------
__global__ void __launch_bounds__(256) kC(const float* __restrict__ kn_t,
                                          const float* __restrict__ W1,
                                          const float* __restrict__ W2,
                                          float* __restrict__ Fbase) {
    const int mat = blockIdx.y;
    const float* W = mat ? W2 : W1;
    float* F = Fbase + (size_t)mat * (K_ * K_);
    __shared__ float knl[8][D_];
    const int k0 = blockIdx.x * 8;
    for (int i = threadIdx.x; i < 8 * D_; i += 256)
        knl[i >> 6][i & 63] = kn_t[k0 * D_ + i];
    __syncthreads();
    for (int n = threadIdx.x; n < K_; n += 256) {
        const float* wr = W + (size_t)n * KD_ + K_;
        float4 wv[16];
#pragma unroll
        for (int j = 0; j < 16; j++) wv[j] = *(const float4*)(wr + 4 * j);
#pragma unroll
        for (int kk = 0; kk < 8; kk++) {
            float acc = 0.f;
#pragma unroll
            for (int j = 0; j < 16; j++) {
                acc = fmaf(knl[kk][4*j],   wv[j].x, acc);
                acc = fmaf(knl[kk][4*j+1], wv[j].y, acc);
                acc = fmaf(knl[kk][4*j+2], wv[j].z, acc);
                acc = fmaf(knl[kk][4*j+3], wv[j].w, acc);
            }
            F[(size_t)(k0 + kk) * K_ + n] = fexp2(-LOG2E * acc);
        }
    }
}

// ---------------------------------------------------------------------------
// KMain: for each (b,k): t = sum_n ( 1/(1+E1[b,n]F1[k,n]) - 1/(1+E2[b,n]F2[k,n]) ) * W3[n]
//        o = sigmoid(t + b3);  partial[b, col] = sum over this wave's k of o*kn_emb[b,k]
// grid: (K_/32, B_/4), block 256 (4 waves). Wave w handles k in [bx*32+w*8, +8), 4 b's.
// ---------------------------------------------------------------------------
__global__ void __launch_bounds__(256) kMain(const float* __restrict__ Ebase,
                                             const float* __restrict__ Fbase,
                                             const float* __restrict__ W3,
                                             const float* __restrict__ b3,
                                             const float* __restrict__ kn_emb,
                                             float* __restrict__ partial) {
    const int lane = threadIdx.x & 63;
    const int wave = threadIdx.x >> 6;
    const int b0 = blockIdx.y * 4;
    const int kbase = blockIdx.x * 32 + wave * 8;
    const float* E1 = Ebase;
    const float* E2 = Ebase + B_ * K_;
    const float* F1 = Fbase;
    const float* F2 = Fbase + K_ * K_;

    float e1[4][8], e2[4][8], w3r[8];
#pragma unroll
    for (int c = 0; c < 8; c++) {
        w3r[c] = W3[c * 64 + lane];
#pragma unroll
        for (int bi = 0; bi < 4; bi++) {
            e1[bi][c] = E1[(size_t)(b0 + bi) * K_ + c * 64 + lane];
            e2[bi][c] = E2[(size_t)(b0 + bi) * K_ + c * 64 + lane];
        }
    }
    const float b3v = b3[0];
    float sum[4] = {0.f, 0.f, 0.f, 0.f};

    for (int kk = 0; kk < 8; kk++) {
        const int k = kbase + kk;
        const float* f1r = F1 + (size_t)k * K_;
        const float* f2r = F2 + (size_t)k * K_;
        float acc[4] = {0.f, 0.f, 0.f, 0.f};
#pragma unroll
        for (int c = 0; c < 8; c++) {
            const float f1 = f1r[c * 64 + lane];
            const float f2 = f2r[c * 64 + lane];
#pragma unroll
            for (int bi = 0; bi < 4; bi++) {
                const float p = frcp(fmaf(e1[bi][c], f1, 1.0f));
                const float q = frcp(fmaf(e2[bi][c], f2, 1.0f));
                acc[bi] = fmaf(p - q, w3r[c], acc[bi]);
            }
        }
#pragma unroll
        for (int bi = 0; bi < 4; bi++) {
            float t = acc[bi];
#pragma unroll
            for (int off = 32; off; off >>= 1) t += __shfl_xor(t, off, 64);
            const float o = fsig(t + b3v);
            const float kv = kn_emb[(size_t)(b0 + bi) * K_ + k];
            sum[bi] = fmaf(o, kv, sum[bi]);
        }
    }
    if (lane == 0) {
        const int col = blockIdx.x * 4 + wave;  // 0..63
#pragma unroll
        for (int bi = 0; bi < 4; bi++)
            partial[(size_t)(b0 + bi) * 64 + col] = sum[bi];
    }
}

// ---------------------------------------------------------------------------
// KFin: out[b] = sum(partial[b,:]) / sum(kn_emb[b,:])
// grid: B_ blocks x 64 threads
// ---------------------------------------------------------------------------
__global__ void __launch_bounds__(64) kFin(const float* __restrict__ partial,
                                           const float* __restrict__ kn_emb,
                                           float* __restrict__ out) {
    const int b = blockIdx.x;
    const int lane = threadIdx.x;
    float num = partial[(size_t)b * 64 + lane];
    float den = 0.f;
#pragma unroll
    for (int c = 0; c < 8; c++) den += kn_emb[(size_t)b * K_ + c * 64 + lane];
#pragma unroll
    for (int off = 32; off; off >>= 1) {
        num += __shfl_xor(num, off, 64);
        den += __shfl_xor(den, off, 64);
    }
    if (lane == 0) out[b] = num / den;
}

extern "C" void kernel_launch(void* const* d_in, const int* in_sizes, int n_in,
                              void* d_out, int out_size, void* d_ws, size_t ws_size,
                              hipStream_t stream) {
    const int*   stu_id     = (const int*)d_in[0];
    const int*   exer_id    = (const int*)d_in[1];
    const float* kn_emb     = (const float*)d_in[2];
    const float* stu_table  = (const float*)d_in[3];
    const float* exer_table = (const float*)d_in[4];
    const float* kn_table   = (const float*)d_in[5];
    const float* W1         = (const float*)d_in[6];
    const float* W2         = (const float*)d_in[7];
    const float* W3         = (const float*)d_in[8];
    const float* b3         = (const float*)d_in[9];
    float* out = (float*)d_out;

    float* ws      = (float*)d_ws;
    float* S       = ws;                         // 2 * B*K
    float* Ebase   = ws + 2 * B_ * K_;           // 2 * B*K
    float* Fbase   = ws + 4 * B_ * K_;           // 2 * K*K
    float* partial = Fbase + 2 * K_ * K_;        // B * 64

    kS<<<B_, 256, 0, stream>>>(stu_id, exer_id, stu_table, exer_table, kn_table,
                               S, S + B_ * K_);
    kA<<<dim3(K_ / 64, B_ / 4, 2), 64, 0, stream>>>(S, W1, W2, Ebase);
    kC<<<dim3(K_ / 8, 2), 256, 0, stream>>>(kn_table, W1, W2, Fbase);
    kMain<<<dim3(K_ / 32, B_ / 4), 256, 0, stream>>>(Ebase, Fbase, W3, b3, kn_emb, partial);
    kFin<<<B_, 64, 0, stream>>>(partial, kn_emb, out);
}